// Round 5
// baseline (663.675 us; speedup 1.0000x reference)
//
#include <hip/hip_runtime.h>
#include <math.h>

typedef unsigned long long ull;

#define N      96
#define NN     9216
#define LAT    256
#define ODIM   4656
#define CH     128      // k-chunks for encoder GEMV partials
#define RPC    72       // rows per chunk (128*72 = 9216)
#define ITERS  50
#define CB     12       // mpm blocks
#define CT     768      // threads per mpm block (12 waves)
#define CPB    8        // columns per block

#define SENT_F   -1.0f
#define SENT_U   0xBF800000u
#define SENTPAIR 0xBF800000BF800000ULL

// ---- workspace layout (float offsets) ----
#define WS_PART  0                      // [2][CH][LAT] = 65536
#define WS_OUTS  65536                  // 4656 sigmoid outputs
#define WS_KL    70192                  // 1
#define WS_BCE   70193                  // 1 (atomic accumulator)
#define WS_NSLOT 70208                  // [4][12][16] floats = 768 (64B/slot)
#define WS_XBUF  70976                  // [4][9216] floats, row-major x, 8B aligned

__device__ __forceinline__ int tri(int i, int j) {   // i <= j
    return i * N - i * (i - 1) / 2 + (j - i);
}

__device__ __forceinline__ int tri_row(int o) {
    int i = (int)floorf((193.0f - sqrtf((float)(37249 - 8 * o))) * 0.5f);
    i = max(0, min(95, i));
    while ((i + 1) * N - (i + 1) * i / 2 <= o) ++i;
    while (i * N - i * (i - 1) / 2 > o) --i;
    return i;
}

// ---- kA: encoder GEMV partials + control/sentinel init ----
__global__ __launch_bounds__(256) void kA_gemv(const float* __restrict__ h,
                                               const float* __restrict__ W1,
                                               const float* __restrict__ W2,
                                               float* __restrict__ ws) {
    __shared__ float hs[RPC];
    int t = threadIdx.x, c = blockIdx.x;
    if (c == 0) {
        if (t < 2) ws[WS_KL + t] = 0.f;                        // KL, BCE
        for (int z = t; z < 4 * CB * 16; z += 256) ws[WS_NSLOT + z] = SENT_F;
    }
    // all 4 x-banks -> sentinel (spread across all kA blocks)
    for (int z = c * 256 + t; z < 4 * NN; z += CH * 256) ws[WS_XBUF + z] = SENT_F;
    int k0 = c * RPC;
    if (t < RPC) hs[t] = h[k0 + t];
    __syncthreads();
    float a1 = 0.f, a2 = 0.f;
    #pragma unroll 4
    for (int kk = 0; kk < RPC; ++kk) {
        float hv = hs[kk];
        a1 = fmaf(hv, W1[(k0 + kk) * LAT + t], a1);
        a2 = fmaf(hv, W2[(k0 + kk) * LAT + t], a2);
    }
    ws[WS_PART + c * LAT + t]        = a1;
    ws[WS_PART + (CH + c) * LAT + t] = a2;
}

// ---- kB: reduce partials -> z ; KL ; decoder ; sigmoid ; BCE ----
__global__ __launch_bounds__(256) void kB_dec(const float* __restrict__ eps,
                                              const float* __restrict__ be11,
                                              const float* __restrict__ be12,
                                              const float* __restrict__ Wd1,
                                              const float* __restrict__ bd1,
                                              const float* __restrict__ Wd2,
                                              const float* __restrict__ bd2,
                                              const float* __restrict__ adj,
                                              float* __restrict__ ws) {
    __shared__ float zi[LAT];
    __shared__ float hid[LAT];
    __shared__ float red[256];
    int t = threadIdx.x;
    const float* p = ws + WS_PART;
    float mu = 0.f, ls = 0.f;
    #pragma unroll 8
    for (int c = 0; c < CH; ++c) {
        mu += p[c * LAT + t];
        ls += p[(CH + c) * LAT + t];
    }
    mu += be11[t];
    ls += be12[t];
    zi[t] = eps[t] * expf(0.5f * ls) + mu;
    red[t] = 1.0f + ls - mu * mu - expf(ls);
    __syncthreads();
    for (int s = 128; s > 0; s >>= 1) {
        if (t < s) red[t] += red[t + s];
        __syncthreads();
    }
    if (blockIdx.x == 0 && t == 0) ws[WS_KL] = -0.5f * red[0] / 9216.0f;
    __syncthreads();
    float acc = 0.f;
    #pragma unroll 8
    for (int k = 0; k < LAT; ++k) acc = fmaf(zi[k], Wd1[k * LAT + t], acc);
    hid[t] = fmaxf(acc + bd1[t], 0.f);
    __syncthreads();
    int o = blockIdx.x * 256 + t;
    float term = 0.f;
    if (o < ODIM) {
        float a2 = 0.f;
        #pragma unroll 8
        for (int k = 0; k < LAT; ++k) a2 = fmaf(hid[k], Wd2[k * ODIM + o], a2);
        float y = a2 + bd2[o];
        float s = 1.0f / (1.0f + expf(-y));
        ws[WS_OUTS + o] = s;
        int i = tri_row(o);
        int j = i + (o - (i * N - i * (i - 1) / 2));
        float inp = adj[i * N + j];
        float li = fmaxf(logf(inp), -100.0f);
        float l1 = fmaxf(log1pf(-inp), -100.0f);
        term = s * li + (1.0f - s) * l1;
    }
    red[t] = term;
    __syncthreads();
    for (int s = 128; s > 0; s >>= 1) {
        if (t < s) red[t] += red[t + s];
        __syncthreads();
    }
    if (t == 0) atomicAdd(ws + WS_BCE, red[0]);
}

// ---- kC: MPM, 12 blocks x 768 threads, sentinel-word sync, row-major x ----
__global__ __launch_bounds__(CT, 3) void kC_mpm(const float* __restrict__ adj,
                                                float* __restrict__ ws,
                                                float* __restrict__ out) {
    __shared__ __align__(16) float xn[N][100];      // row-major, 16B-aligned rows
    __shared__ __align__(16) float Brow[CPB][N];
    __shared__ __align__(16) float Scol[CPB][N];
    __shared__ __align__(16) float Mv[CPB][N];
    __shared__ float ds[N], drs[N], ft[N];
    __shared__ float ftr_sh[CPB];
    __shared__ float wred[CT / 64];
    __shared__ float s_inv;

    int t = threadIdx.x, bid = blockIdx.x;
    int jj = t % N, al = t / N;          // al 0..7
    int a  = bid * CPB + al;             // global column
    int si = t >> 3, sc = t & 7;         // staging: row si, 12-float chunk sc

    const float* outs = ws + WS_OUTS;
    float* xbuf  = ws + WS_XBUF;         // [4][NN] row-major
    float* nslot = ws + WS_NSLOT;        // [4][CB][16]

    // ---- local build ----
    if (t < N) {
        ds[t]  = adj[t * N + t];
        drs[t] = outs[tri(t, t)];
        const float4* ar = (const float4*)(adj + t * N);
        float s1 = 0.f;
        #pragma unroll
        for (int q = 0; q < N / 4; ++q) {
            float4 v = ar[q];
            s1 += v.x + v.y + v.z + v.w;
        }
        ft[t] = s1;
    }
    __syncthreads();
    {
        int lo = min(a, jj), hi = max(a, jj);
        Mv[al][jj] = outs[tri(lo, hi)];            // rec(a, jj)
    }
    __syncthreads();
    if (t < CPB) {
        float s2 = 0.f;
        for (int b = 0; b < N; ++b) s2 += Mv[t][b];
        ftr_sh[t] = s2;
    }
    __syncthreads();
    Brow[al][jj] = (jj == a) ? 0.f : (Mv[al][jj] * drs[a]) * drs[jj];
    Scol[al][jj] = (ds[jj] * drs[a]) * (1.0f / (fabsf(ft[jj] - ftr_sh[al]) + 1.0f));

    // Aoff row jj, register-resident (iteration-invariant); pin with asm
    float arow[N];
    {
        const float* arp = adj + jj * N;
        float di = ds[jj];
        #pragma unroll
        for (int j = 0; j < N; ++j)
            arow[j] = (j == jj) ? 0.f : (arp[j] * di) * ds[j];
    }
    #pragma unroll
    for (int j = 0; j < N; ++j) asm volatile("" : "+v"(arow[j]));
    __syncthreads();

    // ---- 50 MPM iterations ----
    float acc = 0.f;
    for (int s = 0; s < ITERS; ++s) {
        // ---- stage x_s into LDS (row-major) ----
        if (s == 0) {
            const float v0 = (float)(1.0 / 96.0);
            for (int f = t; f < NN; f += CT) xn[f / N][f % N] = v0;
            if (t == 0) s_inv = 1.0f;              // ||x0|| == 1 exactly
        } else {
            const ull* src = (const ull*)(xbuf + (s & 3) * NN) + (si * 48 + sc * 6);
            union { ull u[6]; float4 q[3]; } U;
            bool ok = false;
            while (!ok) {
                ok = true;
                #pragma unroll
                for (int k = 0; k < 6; ++k)
                    U.u[k] = __hip_atomic_load(&src[k], __ATOMIC_RELAXED,
                                               __HIP_MEMORY_SCOPE_AGENT);
                #pragma unroll
                for (int k = 0; k < 6; ++k) {
                    ok &= ((unsigned)U.u[k] != SENT_U);
                    ok &= ((unsigned)(U.u[k] >> 32) != SENT_U);
                }
                if (!ok) __builtin_amdgcn_s_sleep(1);
            }
            float4* dst = (float4*)&xn[si][sc * 12];
            dst[0] = U.q[0]; dst[1] = U.q[1]; dst[2] = U.q[2];
        }
        __syncthreads();                            // sync1

        // ---- phase B: M[jj, a] = max_b Brow[al][b] * x[jj][b] (b128 reads) ----
        float m = 0.f;
        #pragma unroll
        for (int q = 0; q < N / 4; ++q) {
            float4 xv = *(const float4*)&xn[jj][q * 4];
            float4 bw = *(const float4*)&Brow[al][q * 4];
            m = fmaxf(m, bw.x * xv.x);
            m = fmaxf(m, bw.y * xv.y);
            m = fmaxf(m, bw.z * xv.z);
            m = fmaxf(m, bw.w * xv.w);
        }
        Mv[al][jj] = m;

        // ---- norm poll (wave 0; value landed ~1 iteration ago -> no wait) ----
        if (s > 0 && t < 64) {
            float pv = 0.f;
            bool done = (t >= CB);
            const unsigned* np = (const unsigned*)(nslot + (s & 3) * CB * 16);
            while (!__all(done)) {
                if (!done) {
                    unsigned u = __hip_atomic_load(&np[t * 16], __ATOMIC_RELAXED,
                                                   __HIP_MEMORY_SCOPE_AGENT);
                    if (u != SENT_U) { pv = __uint_as_float(u); done = true; }
                }
                __builtin_amdgcn_s_sleep(1);
            }
            #pragma unroll
            for (int off = 8; off > 0; off >>= 1) pv += __shfl_xor(pv, off, 16);
            if (t == 0) s_inv = 1.0f / sqrtf(pv);
        }
        __syncthreads();                            // sync2 (Mv + s_inv ready)

        // ---- phase C: x_new[jj,a] = x[jj][a]*Sd + sum_j arow[j]*M[j,a] ----
        float r = xn[jj][a] * Scol[al][jj];
        #pragma unroll
        for (int q = 0; q < N / 4; ++q) {
            float4 mv = *(const float4*)&Mv[al][q * 4];
            r = fmaf(arow[q * 4 + 0], mv.x, r);
            r = fmaf(arow[q * 4 + 1], mv.y, r);
            r = fmaf(arow[q * 4 + 2], mv.z, r);
            r = fmaf(arow[q * 4 + 3], mv.w, r);
        }
        acc = r * s_inv;

        // publish x_{s+1}[jj][a] (relaxed b32, fire-and-forget)
        if (s < ITERS - 1)
            __hip_atomic_store((unsigned*)(xbuf + ((s + 1) & 3) * NN) + (jj * N + a),
                               __float_as_uint(acc), __ATOMIC_RELAXED,
                               __HIP_MEMORY_SCOPE_AGENT);
        // sentinel-refresh own staging slice of bank (s+3)&3
        if (s < ITERS - 3) {
            ull* rb = (ull*)(xbuf + ((s + 3) & 3) * NN) + (si * 48 + sc * 6);
            #pragma unroll
            for (int k = 0; k < 6; ++k)
                __hip_atomic_store(&rb[k], SENTPAIR, __ATOMIC_RELAXED,
                                   __HIP_MEMORY_SCOPE_AGENT);
        }

        // block partial of ||x_{s+1}||^2
        float ssq = acc * acc;
        #pragma unroll
        for (int off = 32; off > 0; off >>= 1) ssq += __shfl_xor(ssq, off);
        if ((t & 63) == 0) wred[t >> 6] = ssq;
        __syncthreads();                            // sync3 (wred + xn WAR)
        if (t == 0) {
            float sum = 0.f;
            #pragma unroll
            for (int w = 0; w < CT / 64; ++w) sum += wred[w];
            __hip_atomic_store((unsigned*)(nslot + ((s + 1) & 3) * CB * 16 + bid * 16),
                               __float_as_uint(sum), __ATOMIC_RELAXED,
                               __HIP_MEMORY_SCOPE_AGENT);
            if (s < ITERS - 2)
                __hip_atomic_store((unsigned*)(nslot + ((s + 3) & 3) * CB * 16 + bid * 16),
                                   SENT_U, __ATOMIC_RELAXED,
                                   __HIP_MEMORY_SCOPE_AGENT);
        }
    }

    // ---- final normalize (poll ||x_50||^2), write output ----
    if (t < 64) {
        float pv = 0.f;
        bool done = (t >= CB);
        const unsigned* np = (const unsigned*)(nslot + (ITERS & 3) * CB * 16);
        while (!__all(done)) {
            if (!done) {
                unsigned u = __hip_atomic_load(&np[t * 16], __ATOMIC_RELAXED,
                                               __HIP_MEMORY_SCOPE_AGENT);
                if (u != SENT_U) { pv = __uint_as_float(u); done = true; }
            }
            __builtin_amdgcn_s_sleep(1);
        }
        #pragma unroll
        for (int off = 8; off > 0; off >>= 1) pv += __shfl_xor(pv, off, 16);
        if (t == 0) s_inv = 1.0f / sqrtf(pv);
    }
    __syncthreads();
    out[1 + jj * N + a] = acc * s_inv;
    if (bid == 0 && t == 0)
        out[0] = -(ws[WS_BCE] / 4656.0f) + ws[WS_KL];
}

extern "C" void kernel_launch(void* const* d_in, const int* in_sizes, int n_in,
                              void* d_out, int out_size, void* d_ws, size_t ws_size,
                              hipStream_t stream) {
    const float* inf  = (const float*)d_in[0];
    const float* adj  = (const float*)d_in[1];
    const float* eps  = (const float*)d_in[2];
    const float* We11 = (const float*)d_in[3];
    const float* be11 = (const float*)d_in[4];
    const float* We12 = (const float*)d_in[5];
    const float* be12 = (const float*)d_in[6];
    const float* Wd1  = (const float*)d_in[7];
    const float* bd1  = (const float*)d_in[8];
    const float* Wd2  = (const float*)d_in[9];
    const float* bd2  = (const float*)d_in[10];
    float* ws  = (float*)d_ws;
    float* out = (float*)d_out;

    kA_gemv<<<CH, 256, 0, stream>>>(inf, We11, We12, ws);
    kB_dec <<<19, 256, 0, stream>>>(eps, be11, be12, Wd1, bd1, Wd2, bd2, adj, ws);
    kC_mpm <<<CB, CT, 0, stream>>>(adj, ws, out);
}

// Round 7
// 426.866 us; speedup vs baseline: 1.5548x; 1.5548x over previous
//
#include <hip/hip_runtime.h>
#include <math.h>

typedef unsigned long long ull;

#define N      96
#define NN     9216
#define LAT    256
#define ODIM   4656
#define CH     128      // k-chunks for encoder GEMV partials
#define RPC    72       // rows per chunk (128*72 = 9216)
#define ITERS  50
#define CB     12       // mpm blocks
#define CT     768      // threads per mpm block (12 waves)
#define CPB    8        // columns per block

#define SGNMASK2 0x8000000080000000ULL
#define ABSMASK2 0x7FFFFFFF7FFFFFFFULL

// ---- workspace layout (float offsets) ----
#define WS_PART  0                      // [2][CH][LAT] = 65536
#define WS_OUTS  65536                  // 4656 sigmoid outputs
#define WS_KL    70192                  // 1
#define WS_BCE   70193                  // 1 (atomic accumulator)
#define WS_NSLOT 70208                  // [2][12][16] floats = 384 (64B/slot)
#define WS_XBUF  70592                  // [2][9216] floats, row-major x, 8B aligned

__device__ __forceinline__ int tri(int i, int j) {   // i <= j
    return i * N - i * (i - 1) / 2 + (j - i);
}

__device__ __forceinline__ int tri_row(int o) {
    int i = (int)floorf((193.0f - sqrtf((float)(37249 - 8 * o))) * 0.5f);
    i = max(0, min(95, i));
    while ((i + 1) * N - (i + 1) * i / 2 <= o) ++i;
    while (i * N - i * (i - 1) / 2 > o) --i;
    return i;
}

// ---- kA: encoder GEMV partials + control-word init ----
// x/norm banks carry a sign-bit tag: stage s lives in bank (s&1) with
// sign bit ((s>>1)&1). Init bank0 = +0 (invalid for its first expected
// tag 1... bank0 first used at s=2 expecting tag 1), bank1 = -0
// (invalid for s=1's expected tag 0).
__global__ __launch_bounds__(256) void kA_gemv(const float* __restrict__ h,
                                               const float* __restrict__ W1,
                                               const float* __restrict__ W2,
                                               float* __restrict__ ws) {
    __shared__ float hs[RPC];
    int t = threadIdx.x, c = blockIdx.x;
    if (c == 0) {
        if (t < 2) ws[WS_KL + t] = 0.f;                        // KL, BCE
        if (t < CB * 16) {
            ws[WS_NSLOT + t]           = 0.0f;                 // bank0: +0
            ws[WS_NSLOT + CB * 16 + t] = -0.0f;                // bank1: -0
        }
    }
    for (int z = c * 256 + t; z < NN; z += CH * 256) {
        ws[WS_XBUF + z]      = 0.0f;                           // bank0: +0
        ws[WS_XBUF + NN + z] = -0.0f;                          // bank1: -0
    }
    int k0 = c * RPC;
    if (t < RPC) hs[t] = h[k0 + t];
    __syncthreads();
    float a1 = 0.f, a2 = 0.f;
    #pragma unroll 4
    for (int kk = 0; kk < RPC; ++kk) {
        float hv = hs[kk];
        a1 = fmaf(hv, W1[(k0 + kk) * LAT + t], a1);
        a2 = fmaf(hv, W2[(k0 + kk) * LAT + t], a2);
    }
    ws[WS_PART + c * LAT + t]        = a1;
    ws[WS_PART + (CH + c) * LAT + t] = a2;
}

// ---- kB: reduce partials -> z ; KL ; decoder ; sigmoid ; BCE ----
__global__ __launch_bounds__(256) void kB_dec(const float* __restrict__ eps,
                                              const float* __restrict__ be11,
                                              const float* __restrict__ be12,
                                              const float* __restrict__ Wd1,
                                              const float* __restrict__ bd1,
                                              const float* __restrict__ Wd2,
                                              const float* __restrict__ bd2,
                                              const float* __restrict__ adj,
                                              float* __restrict__ ws) {
    __shared__ float zi[LAT];
    __shared__ float hid[LAT];
    __shared__ float red[256];
    int t = threadIdx.x;
    const float* p = ws + WS_PART;
    float mu = 0.f, ls = 0.f;
    #pragma unroll 8
    for (int c = 0; c < CH; ++c) {
        mu += p[c * LAT + t];
        ls += p[(CH + c) * LAT + t];
    }
    mu += be11[t];
    ls += be12[t];
    zi[t] = eps[t] * expf(0.5f * ls) + mu;
    red[t] = 1.0f + ls - mu * mu - expf(ls);
    __syncthreads();
    for (int s = 128; s > 0; s >>= 1) {
        if (t < s) red[t] += red[t + s];
        __syncthreads();
    }
    if (blockIdx.x == 0 && t == 0) ws[WS_KL] = -0.5f * red[0] / 9216.0f;
    __syncthreads();
    float acc = 0.f;
    #pragma unroll 8
    for (int k = 0; k < LAT; ++k) acc = fmaf(zi[k], Wd1[k * LAT + t], acc);
    hid[t] = fmaxf(acc + bd1[t], 0.f);
    __syncthreads();
    int o = blockIdx.x * 256 + t;
    float term = 0.f;
    if (o < ODIM) {
        float a2 = 0.f;
        #pragma unroll 8
        for (int k = 0; k < LAT; ++k) a2 = fmaf(hid[k], Wd2[k * ODIM + o], a2);
        float y = a2 + bd2[o];
        float s = 1.0f / (1.0f + expf(-y));
        ws[WS_OUTS + o] = s;
        int i = tri_row(o);
        int j = i + (o - (i * N - i * (i - 1) / 2));
        float inp = adj[i * N + j];
        float li = fmaxf(logf(inp), -100.0f);
        float l1 = fmaxf(log1pf(-inp), -100.0f);
        term = s * li + (1.0f - s) * l1;
    }
    red[t] = term;
    __syncthreads();
    for (int s = 128; s > 0; s >>= 1) {
        if (t < s) red[t] += red[t + s];
        __syncthreads();
    }
    if (t == 0) atomicAdd(ws + WS_BCE, red[0]);
}

// ---- kC: MPM, 12 blocks x 768 threads, sign-tagged sync, row-major x ----
__global__ __launch_bounds__(CT, 3) void kC_mpm(const float* __restrict__ adj,
                                                float* __restrict__ ws,
                                                float* __restrict__ out) {
    __shared__ __align__(16) float xn[N][100];      // row-major, 16B-aligned rows
    __shared__ __align__(16) float Brow[CPB][N];
    __shared__ __align__(16) float Scol[CPB][N];
    __shared__ __align__(16) float Mv[CPB][N];
    __shared__ __align__(16) float Pout[N][CPB];    // publish transpose tile
    __shared__ float ds[N], drs[N], ft[N];
    __shared__ float ftr_sh[CPB];
    __shared__ float wred[CT / 64];
    __shared__ float s_inv;

    int t = threadIdx.x, bid = blockIdx.x;
    int jj = t % N, al = t / N;          // al 0..7
    int a  = bid * CPB + al;             // global column
    int si = t >> 3, sc = t & 7;         // staging: row si, 12-float chunk sc

    const float* outs = ws + WS_OUTS;
    float* xbuf  = ws + WS_XBUF;         // [2][NN] row-major
    float* nslot = ws + WS_NSLOT;        // [2][CB][16]

    // ---- local build ----
    if (t < N) {
        ds[t]  = adj[t * N + t];
        drs[t] = outs[tri(t, t)];
        const float4* ar = (const float4*)(adj + t * N);
        float s1 = 0.f;
        #pragma unroll
        for (int q = 0; q < N / 4; ++q) {
            float4 v = ar[q];
            s1 += v.x + v.y + v.z + v.w;
        }
        ft[t] = s1;
    }
    __syncthreads();
    {
        int lo = min(a, jj), hi = max(a, jj);
        Mv[al][jj] = outs[tri(lo, hi)];            // rec(a, jj)
    }
    __syncthreads();
    if (t < CPB) {
        float s2 = 0.f;
        for (int b = 0; b < N; ++b) s2 += Mv[t][b];
        ftr_sh[t] = s2;
    }
    __syncthreads();
    Brow[al][jj] = (jj == a) ? 0.f : (Mv[al][jj] * drs[a]) * drs[jj];
    Scol[al][jj] = (ds[jj] * drs[a]) * (1.0f / (fabsf(ft[jj] - ftr_sh[al]) + 1.0f));

    // Aoff row jj (iteration-invariant; compiler may remat from L1 - fine)
    float arow[N];
    {
        const float* arp = adj + jj * N;
        float di = ds[jj];
        #pragma unroll
        for (int j = 0; j < N; ++j)
            arow[j] = (j == jj) ? 0.f : (arp[j] * di) * ds[j];
    }
    __syncthreads();

    // ---- 50 MPM iterations ----
    float acc = 0.f;
    for (int s = 0; s < ITERS; ++s) {
        // ---- stage x_s into LDS (row-major), sign-tag poll ----
        if (s == 0) {
            const float v0 = (float)(1.0 / 96.0);
            for (int f = t; f < NN; f += CT) xn[f / N][f % N] = v0;
            if (t == 0) s_inv = 1.0f;              // ||x0|| == 1 exactly
        } else {
            const ull want = ((s >> 1) & 1) ? SGNMASK2 : 0ULL;
            const ull* src = (const ull*)(xbuf + (s & 1) * NN) + (si * 48 + sc * 6);
            union { ull u[6]; float4 q[3]; } U;
            bool ok = false;
            while (!ok) {
                ok = true;
                #pragma unroll
                for (int k = 0; k < 6; ++k)
                    U.u[k] = __hip_atomic_load(&src[k], __ATOMIC_RELAXED,
                                               __HIP_MEMORY_SCOPE_AGENT);
                #pragma unroll
                for (int k = 0; k < 6; ++k)
                    ok &= ((U.u[k] & SGNMASK2) == want);
                if (!ok) __builtin_amdgcn_s_sleep(1);
            }
            #pragma unroll
            for (int k = 0; k < 6; ++k) U.u[k] &= ABSMASK2;
            float4* dst = (float4*)&xn[si][sc * 12];
            dst[0] = U.q[0]; dst[1] = U.q[1]; dst[2] = U.q[2];
        }
        __syncthreads();                            // sync1

        // ---- phase B: M[jj, a] = max_b Brow[al][b] * x[jj][b] ----
        float m = 0.f;
        #pragma unroll
        for (int q = 0; q < N / 4; ++q) {
            float4 xv = *(const float4*)&xn[jj][q * 4];
            float4 bw = *(const float4*)&Brow[al][q * 4];
            m = fmaxf(m, bw.x * xv.x);
            m = fmaxf(m, bw.y * xv.y);
            m = fmaxf(m, bw.z * xv.z);
            m = fmaxf(m, bw.w * xv.w);
        }
        Mv[al][jj] = m;

        // ---- norm poll (wave 0; landed with x_s publish -> usually instant) ----
        if (s > 0 && t < 64) {
            const unsigned esn = (unsigned)((s >> 1) & 1);
            float pv = 0.f;
            bool done = (t >= CB);
            const unsigned* np = (const unsigned*)(nslot + (s & 1) * CB * 16);
            while (!__all(done)) {
                if (!done) {
                    unsigned u = __hip_atomic_load(&np[t * 16], __ATOMIC_RELAXED,
                                                   __HIP_MEMORY_SCOPE_AGENT);
                    if ((u >> 31) == esn) { pv = __uint_as_float(u & 0x7FFFFFFFu); done = true; }
                }
                __builtin_amdgcn_s_sleep(1);
            }
            #pragma unroll
            for (int off = 8; off > 0; off >>= 1) pv += __shfl_xor(pv, off, 16);
            if (t == 0) s_inv = 1.0f / sqrtf(pv);
        }
        __syncthreads();                            // sync2 (Mv + s_inv ready)

        // ---- phase C: x_new[jj,a] = x[jj][a]*Sd + sum_j arow[j]*M[j,a] ----
        float r = xn[jj][a] * Scol[al][jj];
        #pragma unroll
        for (int q = 0; q < N / 4; ++q) {
            float4 mv = *(const float4*)&Mv[al][q * 4];
            r = fmaf(arow[q * 4 + 0], mv.x, r);
            r = fmaf(arow[q * 4 + 1], mv.y, r);
            r = fmaf(arow[q * 4 + 2], mv.z, r);
            r = fmaf(arow[q * 4 + 3], mv.w, r);
        }
        acc = r * s_inv;
        Pout[jj][al] = acc;

        // block partial of ||x_{s+1}||^2
        float ssq = acc * acc;
        #pragma unroll
        for (int off = 32; off > 0; off >>= 1) ssq += __shfl_xor(ssq, off);
        if ((t & 63) == 0) wred[t >> 6] = ssq;
        __syncthreads();                            // sync3 (Pout + wred; xn WAR)

        const unsigned tag1 = (unsigned)(((s + 1) >> 1) & 1);
        // coalesced publish: 384 contiguous packed-ull stores (sign-tagged)
        if (s < ITERS - 1 && t < 384) {
            int jjp = t >> 2, c = t & 3;
            float2 pr = *(const float2*)&Pout[jjp][c * 2];
            ull v = (ull)__float_as_uint(pr.x) | ((ull)__float_as_uint(pr.y) << 32);
            if (tag1) v |= SGNMASK2;               // acc >= 0 -> sign bits were 0
            __hip_atomic_store((ull*)(xbuf + ((s + 1) & 1) * NN) + (jjp * 48 + bid * 4 + c),
                               v, __ATOMIC_RELAXED, __HIP_MEMORY_SCOPE_AGENT);
        }
        if (t == 0) {
            float sum = 0.f;
            #pragma unroll
            for (int w = 0; w < CT / 64; ++w) sum += wred[w];
            unsigned u = __float_as_uint(sum) | (tag1 << 31);
            __hip_atomic_store((unsigned*)(nslot + ((s + 1) & 1) * CB * 16 + bid * 16),
                               u, __ATOMIC_RELAXED, __HIP_MEMORY_SCOPE_AGENT);
        }
    }

    // ---- final normalize (poll ||x_50||^2), write output ----
    if (t < 64) {
        const unsigned esf = (unsigned)((ITERS >> 1) & 1);
        float pv = 0.f;
        bool done = (t >= CB);
        const unsigned* np = (const unsigned*)(nslot + (ITERS & 1) * CB * 16);
        while (!__all(done)) {
            if (!done) {
                unsigned u = __hip_atomic_load(&np[t * 16], __ATOMIC_RELAXED,
                                               __HIP_MEMORY_SCOPE_AGENT);
                if ((u >> 31) == esf) { pv = __uint_as_float(u & 0x7FFFFFFFu); done = true; }
            }
            __builtin_amdgcn_s_sleep(1);
        }
        #pragma unroll
        for (int off = 8; off > 0; off >>= 1) pv += __shfl_xor(pv, off, 16);
        if (t == 0) s_inv = 1.0f / sqrtf(pv);
    }
    __syncthreads();
    out[1 + jj * N + a] = acc * s_inv;
    if (bid == 0 && t == 0)
        out[0] = -(ws[WS_BCE] / 4656.0f) + ws[WS_KL];
}

extern "C" void kernel_launch(void* const* d_in, const int* in_sizes, int n_in,
                              void* d_out, int out_size, void* d_ws, size_t ws_size,
                              hipStream_t stream) {
    const float* inf  = (const float*)d_in[0];
    const float* adj  = (const float*)d_in[1];
    const float* eps  = (const float*)d_in[2];
    const float* We11 = (const float*)d_in[3];
    const float* be11 = (const float*)d_in[4];
    const float* We12 = (const float*)d_in[5];
    const float* be12 = (const float*)d_in[6];
    const float* Wd1  = (const float*)d_in[7];
    const float* bd1  = (const float*)d_in[8];
    const float* Wd2  = (const float*)d_in[9];
    const float* bd2  = (const float*)d_in[10];
    float* ws  = (float*)d_ws;
    float* out = (float*)d_out;

    kA_gemv<<<CH, 256, 0, stream>>>(inf, We11, We12, ws);
    kB_dec <<<19, 256, 0, stream>>>(eps, be11, be12, Wd1, bd1, Wd2, bd2, adj, ws);
    kC_mpm <<<CB, CT, 0, stream>>>(adj, ws, out);
}